// Round 8
// baseline (227.529 us; speedup 1.0000x reference)
//
#include <hip/hip_runtime.h>
#include <hip/hip_bf16.h>

#define B_ROWS   4096
#define L_LABELS 100000
#define D_DIM    256
#define TOPK     5
#define SLABN    64       // labels per slab
#define NGROUP   8        // N-groups == XCD count
#define SLABBYTES 32768   // SLABN * D_DIM * 2

// two-phase split: phase 1 counts labels [0, CUT) exactly (dense MFMA,
// bf16-converted slice); phase 2 counts [CUT, L_LABELS) for rows still
// below TOPK, reading f32 labels directly with inline bf16 conversion.
// E[survivors] = 4096*5/(CUT+1) ~= 10 at CUT=2048; p2 handles up to 32
// survivors in ONE B-pass (pair-tile).  (100000-2048)/16 = 6122 exact.
#define CUT       2048
#define NSLAB_C   (CUT / SLABN)            // 32 slabs
#define NG2       ((L_LABELS - CUT) / 16)  // 6122 groups, exact
#define P2_BLOCKS 512

typedef __bf16 bf16x8 __attribute__((ext_vector_type(8)));
typedef __bf16 bf16x4 __attribute__((ext_vector_type(4)));
typedef float  f32x4  __attribute__((ext_vector_type(4)));

__device__ __forceinline__ void async16(const void* g, void* l) {
    __builtin_amdgcn_global_load_lds(
        (const __attribute__((address_space(1))) unsigned int*)g,
        (__attribute__((address_space(3))) unsigned int*)l,
        16, 0, 0);
}

// ---------------------------------------------------------------------------
// Kernel 1: threshold s_t + zero state + fused P->bf16 AND L[0,CUT)->bf16.
// Grid 1024x256 = 262144 threads; first 65536 also convert one bf16x8 of Lb.
// ---------------------------------------------------------------------------
__global__ void prep_kernel(const float* __restrict__ P,
                            const float* __restrict__ Lab,
                            const int*   __restrict__ labels,
                            float* __restrict__ s_t,
                            int*   __restrict__ counts,
                            int*   __restrict__ counts2,
                            __hip_bfloat16* __restrict__ Pb,
                            __hip_bfloat16* __restrict__ Lb,
                            int*   __restrict__ done_ctr,
                            int do_conv) {
    int gid = blockIdx.x * blockDim.x + threadIdx.x;
    if (gid == 0) *done_ctr = 0;

    if (do_conv && gid < (CUT * D_DIM / 8)) {
        const float* s = Lab + (size_t)gid * 8;
        float4 a = *(const float4*)s;
        float4 b = *(const float4*)(s + 4);
        bf16x8 v = {(__bf16)a.x, (__bf16)a.y, (__bf16)a.z, (__bf16)a.w,
                    (__bf16)b.x, (__bf16)b.y, (__bf16)b.z, (__bf16)b.w};
        *(bf16x8*)((__bf16*)Lb + (size_t)gid * 8) = v;
    }

    int gwave = gid >> 6;
    int lane  = gid & 63;
    if (gwave >= B_ROWS) return;
    int t = labels[gwave];
    const float4* p4 = (const float4*)(P + (size_t)gwave * D_DIM);
    const float4* l4 = (const float4*)(Lab + (size_t)t * D_DIM);
    float4 a = p4[lane];
    float4 b = l4[lane];
    if (do_conv) {
        bf16x4 pv = {(__bf16)a.x, (__bf16)a.y, (__bf16)a.z, (__bf16)a.w};
        *(bf16x4*)((__bf16*)Pb + (size_t)gwave * D_DIM + lane * 4) = pv;
    }
    float sum = 0.f;
    sum += (float)(__bf16)a.x * (float)(__bf16)b.x;
    sum += (float)(__bf16)a.y * (float)(__bf16)b.y;
    sum += (float)(__bf16)a.z * (float)(__bf16)b.z;
    sum += (float)(__bf16)a.w * (float)(__bf16)b.w;
    #pragma unroll
    for (int m = 1; m < 64; m <<= 1) sum += __shfl_xor(sum, m, 64);
    if (lane == 0) {
        s_t[gwave]     = sum;
        counts[gwave]  = 0;
        counts2[gwave] = 0;
    }
}

// ---------------------------------------------------------------------------
// Kernel 2 (c1): v6's proven count GEMM over labels [0, CUT) only.
// 4 slabs per XCD-group; body unchanged from v6 (best full-range = 280us).
// ---------------------------------------------------------------------------
#define CBM 64

__global__ __launch_bounds__(512, 4)
void count_kernel_c1(const __hip_bfloat16* __restrict__ Pb,
                     const __hip_bfloat16* __restrict__ Lb,
                     const int*   __restrict__ labels,
                     const float* __restrict__ s_t,
                     int* __restrict__ counts) {
    __shared__ __align__(16) __bf16 Bs[2 * SLABN * D_DIM];   // 2 x 32 KB

    const int group = blockIdx.x;          // 0..7 -> XCD via %8 dispatch
    const int Mbase = blockIdx.y * CBM;
    const int tid   = threadIdx.x;
    const int wave  = tid >> 6;            // 0..7
    const int lane  = tid & 63;
    const int wm    = wave >> 2;           // 0..1 : 32-row half
    const int wn    = wave & 3;            // 0..3 : 16-label quarter
    const int quad  = lane >> 4;           // 0..3
    const int cc    = lane & 15;           // 0..15

    const int s0 = group * (NSLAB_C / NGROUP);   // 4 slabs per group
    const int s1 = s0 + (NSLAB_C / NGROUP);

    // per-thread DMA source offset for j=0; j-th load adds j*8192 bytes.
    const int qc0  = tid & 31;
    const int rw0  = tid >> 5;
    const int gc0  = (qc0 & 24) | ((qc0 ^ rw0) & 7);
    const int dma0 = rw0 * 512 + gc0 * 16;
    const int ldsw = wave * 1024;          // wave-uniform LDS base (bytes)

    // ---- issue DMA for first slab into buffer 0 ----
    {
        const char* gbase = (const char*)Lb + (size_t)s0 * SLABBYTES;
        #pragma unroll
        for (int j = 0; j < 4; ++j)
            async16(gbase + dma0 + j * 8192,
                    (char*)Bs + ldsw + j * 8192);
    }

    // ---- load stationary A fragments: 32 rows x K=256 per wave ----
    bf16x8 af[2][8];
    #pragma unroll
    for (int mi = 0; mi < 2; ++mi) {
        int row = Mbase + wm * 32 + mi * 16 + cc;
        const __bf16* ap = (const __bf16*)Pb + (size_t)row * D_DIM + quad * 8;
        #pragma unroll
        for (int kb = 0; kb < 8; ++kb)
            af[mi][kb] = *(const bf16x8*)(ap + kb * 32);
    }

    // ---- per-row threshold / label (C/D rows: quad*4 + r) ----
    float sr[2][4];
    int   tr[2][4];
    #pragma unroll
    for (int mi = 0; mi < 2; ++mi)
        #pragma unroll
        for (int r = 0; r < 4; ++r) {
            int row = Mbase + wm * 32 + mi * 16 + quad * 4 + r;
            sr[mi][r] = s_t[row];
            tr[mi][r] = labels[row];
        }

    int cnt[2][4] = {};

    for (int s = s0, it = 0; s < s1; ++s, ++it) {
        __syncthreads();   // waits current slab's DMA (vmcnt 0) + buffer reuse

        // issue next slab's DMA into the other buffer; stays in flight
        if (s + 1 < s1) {
            const char* gbase = (const char*)Lb + (size_t)(s + 1) * SLABBYTES;
            char* lbase = (char*)Bs + (size_t)(~it & 1) * SLABBYTES + ldsw;
            #pragma unroll
            for (int j = 0; j < 4; ++j)
                async16(gbase + dma0 + j * 8192, lbase + j * 8192);
        }

        const __bf16* bp = Bs + (size_t)(it & 1) * (SLABN * D_DIM);

        f32x4 acc[2] = {};
        #pragma unroll
        for (int kb = 0; kb < 8; ++kb) {
            int ci = kb * 4 + quad;
            int qc = (ci & 24) | ((ci ^ cc) & 7);   // col&7 == cc&7
            bf16x8 b = *(const bf16x8*)&bp[(wn * 16 + cc) * D_DIM + qc * 8];
            #pragma unroll
            for (int mi = 0; mi < 2; ++mi)
                acc[mi] = __builtin_amdgcn_mfma_f32_16x16x32_bf16(
                    af[mi][kb], b, acc[mi], 0, 0, 0);
        }

        // epilogue: accumulate beat counts in registers
        int n = s * SLABN + wn * 16 + cc;
        #pragma unroll
        for (int mi = 0; mi < 2; ++mi)
            #pragma unroll
            for (int r = 0; r < 4; ++r) {
                float sv = acc[mi][r];
                bool beat = (n != tr[mi][r]) &&
                            (sv > sr[mi][r] ||
                             (sv == sr[mi][r] && n < tr[mi][r]));
                cnt[mi][r] += beat ? 1 : 0;
            }
    }

    // ---- reduce over the 16 cc lanes, one atomic per (wave, quad, mi, r) ----
    #pragma unroll
    for (int mi = 0; mi < 2; ++mi)
        #pragma unroll
        for (int r = 0; r < 4; ++r) {
            int v = cnt[mi][r];
            v += __shfl_xor(v, 1, 64);
            v += __shfl_xor(v, 2, 64);
            v += __shfl_xor(v, 4, 64);
            v += __shfl_xor(v, 8, 64);
            if (cc == 0) {
                int row = Mbase + wm * 32 + mi * 16 + quad * 4 + r;
                atomicAdd(&counts[row], v);
            }
        }
}

// ---------------------------------------------------------------------------
// Kernel 3 (p2): exact count over [CUT, L_LABELS) for survivors, with
// fused ballot compaction (deterministic) and fused last-block finalize.
// Pair-tile: up to 32 survivors share ONE pass over the 96 MB B stream
// (two A-register sets, one B read). Odd tile duplicated, writes guarded.
// Finalize: device-scope done counter; last block re-reads counts2 via
// atomicAdd(p,0) (coherent) and writes the accuracy.
// ---------------------------------------------------------------------------
__global__ __launch_bounds__(256)
void count_kernel_p2(const __hip_bfloat16* __restrict__ Pb,
                     const float* __restrict__ Lab,
                     const int*   __restrict__ labels,
                     const float* __restrict__ s_t,
                     const int*   __restrict__ counts,
                     int*   __restrict__ counts2,
                     int*   __restrict__ done_ctr,
                     float* __restrict__ out) {
    __shared__ int cnt_s[B_ROWS];    // 16 KB
    __shared__ int surv_s[B_ROWS];   // 16 KB
    __shared__ int ns_s, rank_s;
    __shared__ int sred[4];

    const int tid  = threadIdx.x;
    const int wave = tid >> 6;             // 0..3
    const int lane = tid & 63;
    const int quad = lane >> 4;
    const int cc   = lane & 15;

    #pragma unroll
    for (int i = 0; i < B_ROWS / 256; ++i)
        cnt_s[i * 256 + tid] = counts[i * 256 + tid];
    __syncthreads();

    if (wave == 0) {
        int total = 0;
        for (int base = 0; base < B_ROWS; base += 64) {
            bool sv = cnt_s[base + lane] < TOPK;
            unsigned long long m = __ballot(sv);
            int pos = total + __popcll(m & ((1ull << lane) - 1ull));
            if (sv) surv_s[pos] = base + lane;
            total += __popcll(m);
        }
        if (lane == 0) ns_s = total;
    }
    __syncthreads();

    const int ns = ns_s;
    const int ntiles = (ns + 15) >> 4;

    for (int ti = 0; ti < ntiles; ti += 2) {
        const int  tB  = (ti + 1 < ntiles) ? (ti + 1) : ti;
        const bool dup = (tB == ti);

        int arow0 = surv_s[min(ti * 16 + cc, ns - 1)];
        int arow1 = surv_s[min(tB * 16 + cc, ns - 1)];
        bf16x8 af0[8], af1[8];
        const __bf16* ap0 = (const __bf16*)Pb + (size_t)arow0 * D_DIM + quad * 8;
        const __bf16* ap1 = (const __bf16*)Pb + (size_t)arow1 * D_DIM + quad * 8;
        #pragma unroll
        for (int kb = 0; kb < 8; ++kb) {
            af0[kb] = *(const bf16x8*)(ap0 + kb * 32);
            af1[kb] = *(const bf16x8*)(ap1 + kb * 32);
        }

        float sr2[2][4]; int tr2[2][4], sidx[2][4];
        #pragma unroll
        for (int r = 0; r < 4; ++r) {
            int r0 = surv_s[min(ti * 16 + quad * 4 + r, ns - 1)];
            int r1 = surv_s[min(tB * 16 + quad * 4 + r, ns - 1)];
            sidx[0][r] = r0;        sidx[1][r] = r1;
            sr2[0][r]  = s_t[r0];   sr2[1][r]  = s_t[r1];
            tr2[0][r]  = labels[r0]; tr2[1][r] = labels[r1];
        }

        int c2a[4] = {}, c2b[4] = {};
        for (int g = blockIdx.x * 4 + wave; g < NG2; g += P2_BLOCKS * 4) {
            int Lbase = CUT + g * 16;
            const float* bb = Lab + (size_t)(Lbase + cc) * D_DIM + quad * 8;
            f32x4 acc0 = {}, acc1 = {};
            #pragma unroll
            for (int kb = 0; kb < 8; ++kb) {
                float4 x = *(const float4*)(bb + kb * 32);
                float4 y = *(const float4*)(bb + kb * 32 + 4);
                bf16x8 b = {(__bf16)x.x, (__bf16)x.y, (__bf16)x.z, (__bf16)x.w,
                            (__bf16)y.x, (__bf16)y.y, (__bf16)y.z, (__bf16)y.w};
                acc0 = __builtin_amdgcn_mfma_f32_16x16x32_bf16(af0[kb], b, acc0, 0, 0, 0);
                acc1 = __builtin_amdgcn_mfma_f32_16x16x32_bf16(af1[kb], b, acc1, 0, 0, 0);
            }
            int n = Lbase + cc;
            #pragma unroll
            for (int r = 0; r < 4; ++r) {
                float v0 = acc0[r];
                c2a[r] += ((n != tr2[0][r]) &&
                           (v0 > sr2[0][r] || (v0 == sr2[0][r] && n < tr2[0][r]))) ? 1 : 0;
                float v1 = acc1[r];
                c2b[r] += ((n != tr2[1][r]) &&
                           (v1 > sr2[1][r] || (v1 == sr2[1][r] && n < tr2[1][r]))) ? 1 : 0;
            }
        }

        #pragma unroll
        for (int r = 0; r < 4; ++r) {
            int v = c2a[r];
            v += __shfl_xor(v, 1, 64);
            v += __shfl_xor(v, 2, 64);
            v += __shfl_xor(v, 4, 64);
            v += __shfl_xor(v, 8, 64);
            if (cc == 0 && (ti * 16 + quad * 4 + r) < ns && v)
                atomicAdd(&counts2[sidx[0][r]], v);
            int w = c2b[r];
            w += __shfl_xor(w, 1, 64);
            w += __shfl_xor(w, 2, 64);
            w += __shfl_xor(w, 4, 64);
            w += __shfl_xor(w, 8, 64);
            if (cc == 0 && !dup && (tB * 16 + quad * 4 + r) < ns && w)
                atomicAdd(&counts2[sidx[1][r]], w);
        }
    }

    // ---- fused finalize: last block to arrive computes the accuracy ----
    __threadfence();
    __syncthreads();
    if (tid == 0) rank_s = atomicAdd(done_ctr, 1);
    __syncthreads();
    if (rank_s == P2_BLOCKS - 1) {
        int local = 0;
        for (int i = tid; i < B_ROWS; i += 256) {
            int c2 = atomicAdd(&counts2[i], 0);   // coherent read
            local += (cnt_s[i] + c2 < TOPK) ? 1 : 0;
        }
        #pragma unroll
        for (int m = 1; m < 64; m <<= 1) local += __shfl_xor(local, m, 64);
        if ((tid & 63) == 0) sred[tid >> 6] = local;
        __syncthreads();
        if (tid == 0)
            out[0] = (float)(sred[0] + sred[1] + sred[2] + sred[3]) /
                     (float)B_ROWS;
    }
}

// ---------------------------------------------------------------------------
// Kernel 2 (fallback, R1 path) — only if ws too small for bf16 copies.
// Full-range, bounds-checked; counts2 stays zero.
// ---------------------------------------------------------------------------
#define FBM 128
#define FBN 128
#define FBK 32
#define KPAD 40

__global__ __launch_bounds__(256)
void count_kernel_slow(const float* __restrict__ P,
                       const float* __restrict__ Lab,
                       const int*   __restrict__ labels,
                       const float* __restrict__ s_t,
                       int* __restrict__ counts) {
    __shared__ __align__(16) __bf16 As[FBM][KPAD];
    __shared__ __align__(16) __bf16 Bs[FBN][KPAD];

    const int Nbase = blockIdx.x * FBN;
    const int Mbase = blockIdx.y * FBM;
    const int tid  = threadIdx.x;
    const int lane = tid & 63;
    const int wave = tid >> 6;
    const int wm = wave >> 1;
    const int wn = wave & 1;
    const int quad = lane >> 4;
    const int c    = lane & 15;

    const int srow  = tid >> 1;
    const int skoff = (tid & 1) * 16;
    const int brow_g = min(Nbase + srow, L_LABELS - 1);

    f32x4 acc[4][4] = {};

    for (int Kb = 0; Kb < D_DIM; Kb += FBK) {
        const float* gA = P   + (size_t)(Mbase + srow) * D_DIM + Kb + skoff;
        const float* gB = Lab + (size_t)brow_g        * D_DIM + Kb + skoff;
        #pragma unroll
        for (int i = 0; i < 4; ++i) {
            float4 va = *(const float4*)(gA + i * 4);
            float4 vb = *(const float4*)(gB + i * 4);
            *(bf16x4*)&As[srow][skoff + i * 4] =
                (bf16x4){(__bf16)va.x, (__bf16)va.y, (__bf16)va.z, (__bf16)va.w};
            *(bf16x4*)&Bs[srow][skoff + i * 4] =
                (bf16x4){(__bf16)vb.x, (__bf16)vb.y, (__bf16)vb.z, (__bf16)vb.w};
        }
        __syncthreads();

        bf16x8 afr[4], bfr[4];
        #pragma unroll
        for (int mi = 0; mi < 4; ++mi)
            afr[mi] = *(const bf16x8*)&As[wm * 64 + mi * 16 + c][quad * 8];
        #pragma unroll
        for (int ni = 0; ni < 4; ++ni)
            bfr[ni] = *(const bf16x8*)&Bs[wn * 64 + ni * 16 + c][quad * 8];

        #pragma unroll
        for (int mi = 0; mi < 4; ++mi)
            #pragma unroll
            for (int ni = 0; ni < 4; ++ni)
                acc[mi][ni] = __builtin_amdgcn_mfma_f32_16x16x32_bf16(
                    afr[mi], bfr[ni], acc[mi][ni], 0, 0, 0);
        __syncthreads();
    }

    #pragma unroll
    for (int mi = 0; mi < 4; ++mi) {
        int rowb = Mbase + wm * 64 + mi * 16 + quad * 4;
        #pragma unroll
        for (int r = 0; r < 4; ++r) {
            int   row = rowb + r;
            float st  = s_t[row];
            int   t   = labels[row];
            int   cnt = 0;
            #pragma unroll
            for (int ni = 0; ni < 4; ++ni) {
                int   n = Nbase + wn * 64 + ni * 16 + c;
                float s = acc[mi][ni][r];
                bool beat = (n < L_LABELS) && (n != t) &&
                            (s > st || (s == st && n < t));
                cnt += beat ? 1 : 0;
            }
            cnt += __shfl_xor(cnt, 1, 64);
            cnt += __shfl_xor(cnt, 2, 64);
            cnt += __shfl_xor(cnt, 4, 64);
            cnt += __shfl_xor(cnt, 8, 64);
            if (c == 0 && cnt) atomicAdd(&counts[row], cnt);
        }
    }
}

// ---------------------------------------------------------------------------
// Finalize (slow path only): accuracy = mean(counts + counts2 < TOPK).
// ---------------------------------------------------------------------------
__global__ void finalize_kernel(const int* __restrict__ counts,
                                const int* __restrict__ counts2,
                                float* __restrict__ out) {
    __shared__ int sdata[4];
    int tid = threadIdx.x;
    int local = 0;
    for (int i = tid; i < B_ROWS; i += 256)
        local += (counts[i] + counts2[i] < TOPK) ? 1 : 0;
    #pragma unroll
    for (int m = 1; m < 64; m <<= 1) local += __shfl_xor(local, m, 64);
    if ((tid & 63) == 0) sdata[tid >> 6] = local;
    __syncthreads();
    if (tid == 0)
        out[0] = (float)(sdata[0] + sdata[1] + sdata[2] + sdata[3]) /
                 (float)B_ROWS;
}

extern "C" void kernel_launch(void* const* d_in, const int* in_sizes, int n_in,
                              void* d_out, int out_size, void* d_ws, size_t ws_size,
                              hipStream_t stream) {
    const float* P      = (const float*)d_in[0];
    const float* Lab    = (const float*)d_in[1];
    const int*   labels = (const int*)d_in[2];
    float* out = (float*)d_out;

    float* s_t      = (float*)d_ws;
    int*   counts   = (int*)((char*)d_ws + 16384);
    int*   counts2  = (int*)((char*)d_ws + 32768);
    int*   done_ctr = (int*)((char*)d_ws + 49152);

    const size_t pb_off = 65536;
    const size_t lb_off = pb_off + (size_t)B_ROWS * D_DIM * 2;   // +2 MB
    const size_t need   = lb_off + (size_t)CUT * D_DIM * 2;      // ~3.2 MB

    int fast = (ws_size >= need) ? 1 : 0;
    __hip_bfloat16* Pb = (__hip_bfloat16*)((char*)d_ws + pb_off);
    __hip_bfloat16* Lb = (__hip_bfloat16*)((char*)d_ws + lb_off);

    prep_kernel<<<dim3(B_ROWS / 4), 256, 0, stream>>>(
        P, Lab, labels, s_t, counts, counts2, Pb, Lb, done_ctr, fast);

    if (fast) {
        count_kernel_c1<<<dim3(NGROUP, B_ROWS / CBM), 512, 0, stream>>>(
            Pb, Lb, labels, s_t, counts);
        count_kernel_p2<<<dim3(P2_BLOCKS), 256, 0, stream>>>(
            Pb, Lab, labels, s_t, counts, counts2, done_ctr, out);
    } else {
        dim3 grid((L_LABELS + FBN - 1) / FBN, B_ROWS / FBM);
        count_kernel_slow<<<grid, 256, 0, stream>>>(P, Lab, labels, s_t, counts);
        finalize_kernel<<<1, 256, 0, stream>>>(counts, counts2, out);
    }
}

// Round 9
// 183.593 us; speedup vs baseline: 1.2393x; 1.2393x over previous
//
#include <hip/hip_runtime.h>
#include <hip/hip_bf16.h>

#define B_ROWS   4096
#define L_LABELS 100000
#define D_DIM    256
#define TOPK     5
#define SLABN    64       // labels per slab
#define NGROUP   8        // N-groups == XCD count
#define SLABBYTES 32768   // SLABN * D_DIM * 2

// two-phase split: phase 1 counts labels [0, CUT) exactly (dense MFMA,
// bf16-converted slice); phase 2 counts [CUT, L_LABELS) for rows still
// below TOPK, reading f32 labels directly with inline bf16 conversion.
// E[survivors] = 4096*5/(CUT+1) ~= 10 at CUT=2048; p2's ntiles loop is
// exact for ANY survivor count.  (100000-2048)/16 = 6122 exact groups.
#define CUT       2048
#define NSLAB_C   (CUT / SLABN)            // 32 slabs
#define NG2       ((L_LABELS - CUT) / 16)  // 6122 groups, exact
#define P2_BLOCKS 256

typedef __bf16 bf16x8 __attribute__((ext_vector_type(8)));
typedef __bf16 bf16x4 __attribute__((ext_vector_type(4)));
typedef float  f32x4  __attribute__((ext_vector_type(4)));

__device__ __forceinline__ void async16(const void* g, void* l) {
    __builtin_amdgcn_global_load_lds(
        (const __attribute__((address_space(1))) unsigned int*)g,
        (__attribute__((address_space(3))) unsigned int*)l,
        16, 0, 0);
}

// ---------------------------------------------------------------------------
// Kernel 1: threshold s_t + zero state + fused P->bf16 AND L[0,CUT)->bf16.
// Grid 1024x256 = 262144 threads; first 65536 also convert one bf16x8 of Lb.
// ---------------------------------------------------------------------------
__global__ void prep_kernel(const float* __restrict__ P,
                            const float* __restrict__ Lab,
                            const int*   __restrict__ labels,
                            float* __restrict__ s_t,
                            int*   __restrict__ counts,
                            int*   __restrict__ counts2,
                            __hip_bfloat16* __restrict__ Pb,
                            __hip_bfloat16* __restrict__ Lb,
                            int*   __restrict__ nsurv,
                            int do_conv) {
    int gid = blockIdx.x * blockDim.x + threadIdx.x;
    if (gid == 0) *nsurv = 0;

    if (do_conv && gid < (CUT * D_DIM / 8)) {
        const float* s = Lab + (size_t)gid * 8;
        float4 a = *(const float4*)s;
        float4 b = *(const float4*)(s + 4);
        bf16x8 v = {(__bf16)a.x, (__bf16)a.y, (__bf16)a.z, (__bf16)a.w,
                    (__bf16)b.x, (__bf16)b.y, (__bf16)b.z, (__bf16)b.w};
        *(bf16x8*)((__bf16*)Lb + (size_t)gid * 8) = v;
    }

    int gwave = gid >> 6;
    int lane  = gid & 63;
    if (gwave >= B_ROWS) return;
    int t = labels[gwave];
    const float4* p4 = (const float4*)(P + (size_t)gwave * D_DIM);
    const float4* l4 = (const float4*)(Lab + (size_t)t * D_DIM);
    float4 a = p4[lane];
    float4 b = l4[lane];
    if (do_conv) {
        bf16x4 pv = {(__bf16)a.x, (__bf16)a.y, (__bf16)a.z, (__bf16)a.w};
        *(bf16x4*)((__bf16*)Pb + (size_t)gwave * D_DIM + lane * 4) = pv;
    }
    float sum = 0.f;
    sum += (float)(__bf16)a.x * (float)(__bf16)b.x;
    sum += (float)(__bf16)a.y * (float)(__bf16)b.y;
    sum += (float)(__bf16)a.z * (float)(__bf16)b.z;
    sum += (float)(__bf16)a.w * (float)(__bf16)b.w;
    #pragma unroll
    for (int m = 1; m < 64; m <<= 1) sum += __shfl_xor(sum, m, 64);
    if (lane == 0) {
        s_t[gwave]     = sum;
        counts[gwave]  = 0;
        counts2[gwave] = 0;
    }
}

// ---------------------------------------------------------------------------
// Kernel 2 (c1): v6's proven count GEMM over labels [0, CUT) only.
// 4 slabs per XCD-group; body unchanged from v6 (best full-range = 280us).
// ---------------------------------------------------------------------------
#define CBM 64

__global__ __launch_bounds__(512, 4)
void count_kernel_c1(const __hip_bfloat16* __restrict__ Pb,
                     const __hip_bfloat16* __restrict__ Lb,
                     const int*   __restrict__ labels,
                     const float* __restrict__ s_t,
                     int* __restrict__ counts) {
    __shared__ __align__(16) __bf16 Bs[2 * SLABN * D_DIM];   // 2 x 32 KB

    const int group = blockIdx.x;          // 0..7 -> XCD via %8 dispatch
    const int Mbase = blockIdx.y * CBM;
    const int tid   = threadIdx.x;
    const int wave  = tid >> 6;            // 0..7
    const int lane  = tid & 63;
    const int wm    = wave >> 2;           // 0..1 : 32-row half
    const int wn    = wave & 3;            // 0..3 : 16-label quarter
    const int quad  = lane >> 4;           // 0..3
    const int cc    = lane & 15;           // 0..15

    const int s0 = group * (NSLAB_C / NGROUP);   // 4 slabs per group
    const int s1 = s0 + (NSLAB_C / NGROUP);

    // per-thread DMA source offset for j=0; j-th load adds j*8192 bytes.
    const int qc0  = tid & 31;
    const int rw0  = tid >> 5;
    const int gc0  = (qc0 & 24) | ((qc0 ^ rw0) & 7);
    const int dma0 = rw0 * 512 + gc0 * 16;
    const int ldsw = wave * 1024;          // wave-uniform LDS base (bytes)

    // ---- issue DMA for first slab into buffer 0 ----
    {
        const char* gbase = (const char*)Lb + (size_t)s0 * SLABBYTES;
        #pragma unroll
        for (int j = 0; j < 4; ++j)
            async16(gbase + dma0 + j * 8192,
                    (char*)Bs + ldsw + j * 8192);
    }

    // ---- load stationary A fragments: 32 rows x K=256 per wave ----
    bf16x8 af[2][8];
    #pragma unroll
    for (int mi = 0; mi < 2; ++mi) {
        int row = Mbase + wm * 32 + mi * 16 + cc;
        const __bf16* ap = (const __bf16*)Pb + (size_t)row * D_DIM + quad * 8;
        #pragma unroll
        for (int kb = 0; kb < 8; ++kb)
            af[mi][kb] = *(const bf16x8*)(ap + kb * 32);
    }

    // ---- per-row threshold / label (C/D rows: quad*4 + r) ----
    float sr[2][4];
    int   tr[2][4];
    #pragma unroll
    for (int mi = 0; mi < 2; ++mi)
        #pragma unroll
        for (int r = 0; r < 4; ++r) {
            int row = Mbase + wm * 32 + mi * 16 + quad * 4 + r;
            sr[mi][r] = s_t[row];
            tr[mi][r] = labels[row];
        }

    int cnt[2][4] = {};

    for (int s = s0, it = 0; s < s1; ++s, ++it) {
        __syncthreads();   // waits current slab's DMA (vmcnt 0) + buffer reuse

        // issue next slab's DMA into the other buffer; stays in flight
        if (s + 1 < s1) {
            const char* gbase = (const char*)Lb + (size_t)(s + 1) * SLABBYTES;
            char* lbase = (char*)Bs + (size_t)(~it & 1) * SLABBYTES + ldsw;
            #pragma unroll
            for (int j = 0; j < 4; ++j)
                async16(gbase + dma0 + j * 8192, lbase + j * 8192);
        }

        const __bf16* bp = Bs + (size_t)(it & 1) * (SLABN * D_DIM);

        f32x4 acc[2] = {};
        #pragma unroll
        for (int kb = 0; kb < 8; ++kb) {
            int ci = kb * 4 + quad;
            int qc = (ci & 24) | ((ci ^ cc) & 7);   // col&7 == cc&7
            bf16x8 b = *(const bf16x8*)&bp[(wn * 16 + cc) * D_DIM + qc * 8];
            #pragma unroll
            for (int mi = 0; mi < 2; ++mi)
                acc[mi] = __builtin_amdgcn_mfma_f32_16x16x32_bf16(
                    af[mi][kb], b, acc[mi], 0, 0, 0);
        }

        // epilogue: accumulate beat counts in registers
        int n = s * SLABN + wn * 16 + cc;
        #pragma unroll
        for (int mi = 0; mi < 2; ++mi)
            #pragma unroll
            for (int r = 0; r < 4; ++r) {
                float sv = acc[mi][r];
                bool beat = (n != tr[mi][r]) &&
                            (sv > sr[mi][r] ||
                             (sv == sr[mi][r] && n < tr[mi][r]));
                cnt[mi][r] += beat ? 1 : 0;
            }
    }

    // ---- reduce over the 16 cc lanes, one atomic per (wave, quad, mi, r) ----
    #pragma unroll
    for (int mi = 0; mi < 2; ++mi)
        #pragma unroll
        for (int r = 0; r < 4; ++r) {
            int v = cnt[mi][r];
            v += __shfl_xor(v, 1, 64);
            v += __shfl_xor(v, 2, 64);
            v += __shfl_xor(v, 4, 64);
            v += __shfl_xor(v, 8, 64);
            if (cc == 0) {
                int row = Mbase + wm * 32 + mi * 16 + quad * 4 + r;
                atomicAdd(&counts[row], v);
            }
        }
}

// ---------------------------------------------------------------------------
// Kernel 3: compact rows with count1 < TOPK into survivor list.
// Order nondeterministic (atomic), set deterministic; p2's per-row sums
// are order-independent -> final counts identical.
// ---------------------------------------------------------------------------
__global__ void compact_kernel(const int* __restrict__ counts,
                               int* __restrict__ surv,
                               int* __restrict__ nsurv) {
    int row = blockIdx.x * blockDim.x + threadIdx.x;
    if (row < B_ROWS && counts[row] < TOPK) {
        int idx = atomicAdd(nsurv, 1);
        surv[idx] = row;
    }
}

// ---------------------------------------------------------------------------
// Kernel 4 (p2): exact count over [CUT, L_LABELS) for survivors only.
// Pure scan -- no in-block compaction preamble, no fence, no pair-tile
// (r8 post-mortem: those doubled a latency stall).  Survivors padded to
// 16-row MFMA tiles; B read straight from f32 labels with inline bf16
// conversion (identical cast as c1's staging -> identical MFMA inputs).
// ---------------------------------------------------------------------------
__global__ __launch_bounds__(256)
void count_kernel_p2(const __hip_bfloat16* __restrict__ Pb,
                     const float* __restrict__ Lab,
                     const int*   __restrict__ labels,
                     const float* __restrict__ s_t,
                     const int*   __restrict__ surv,
                     const int*   __restrict__ nsurv,
                     int* __restrict__ counts2) {
    const int tid  = threadIdx.x;
    const int wave = tid >> 6;             // 0..3
    const int lane = tid & 63;
    const int quad = lane >> 4;
    const int cc   = lane & 15;

    const int ns = *nsurv;
    if (ns == 0) return;
    const int ntiles = (ns + 15) >> 4;

    for (int ti = 0; ti < ntiles; ++ti) {
        // A fragments: 16 survivor rows (clamped duplicates are read-only)
        int arow = surv[min(ti * 16 + cc, ns - 1)];
        bf16x8 af2[8];
        const __bf16* ap = (const __bf16*)Pb + (size_t)arow * D_DIM + quad * 8;
        #pragma unroll
        for (int kb = 0; kb < 8; ++kb)
            af2[kb] = *(const bf16x8*)(ap + kb * 32);

        // thresholds/labels for the 4 C/D rows (quad*4 + r) this lane holds
        float sr2[4]; int tr2[4], sidx[4];
        #pragma unroll
        for (int r = 0; r < 4; ++r) {
            int rr  = surv[min(ti * 16 + quad * 4 + r, ns - 1)];
            sidx[r] = rr;
            sr2[r]  = s_t[rr];
            tr2[r]  = labels[rr];
        }

        int cnt2[4] = {};
        for (int g = blockIdx.x * 4 + wave; g < NG2; g += P2_BLOCKS * 4) {
            int Lbase = CUT + g * 16;
            const float* bb = Lab + (size_t)(Lbase + cc) * D_DIM + quad * 8;
            f32x4 acc = {};
            #pragma unroll
            for (int kb = 0; kb < 8; ++kb) {
                float4 x = *(const float4*)(bb + kb * 32);
                float4 y = *(const float4*)(bb + kb * 32 + 4);
                bf16x8 b = {(__bf16)x.x, (__bf16)x.y, (__bf16)x.z, (__bf16)x.w,
                            (__bf16)y.x, (__bf16)y.y, (__bf16)y.z, (__bf16)y.w};
                acc = __builtin_amdgcn_mfma_f32_16x16x32_bf16(
                    af2[kb], b, acc, 0, 0, 0);
            }
            int n = Lbase + cc;            // C/D col = label = cc
            #pragma unroll
            for (int r = 0; r < 4; ++r) {
                float sv = acc[r];
                bool beat = (n != tr2[r]) &&
                            (sv > sr2[r] || (sv == sr2[r] && n < tr2[r]));
                cnt2[r] += beat ? 1 : 0;
            }
        }

        #pragma unroll
        for (int r = 0; r < 4; ++r) {
            int v = cnt2[r];
            v += __shfl_xor(v, 1, 64);
            v += __shfl_xor(v, 2, 64);
            v += __shfl_xor(v, 4, 64);
            v += __shfl_xor(v, 8, 64);
            if (cc == 0 && (ti * 16 + quad * 4 + r) < ns && v)
                atomicAdd(&counts2[sidx[r]], v);
        }
    }
}

// ---------------------------------------------------------------------------
// Kernel 2 (fallback, R1 path) — only if ws too small for bf16 copies.
// Full-range, bounds-checked; counts2 stays zero.
// ---------------------------------------------------------------------------
#define FBM 128
#define FBN 128
#define FBK 32
#define KPAD 40

__global__ __launch_bounds__(256)
void count_kernel_slow(const float* __restrict__ P,
                       const float* __restrict__ Lab,
                       const int*   __restrict__ labels,
                       const float* __restrict__ s_t,
                       int* __restrict__ counts) {
    __shared__ __align__(16) __bf16 As[FBM][KPAD];
    __shared__ __align__(16) __bf16 Bs[FBN][KPAD];

    const int Nbase = blockIdx.x * FBN;
    const int Mbase = blockIdx.y * FBM;
    const int tid  = threadIdx.x;
    const int lane = tid & 63;
    const int wave = tid >> 6;
    const int wm = wave >> 1;
    const int wn = wave & 1;
    const int quad = lane >> 4;
    const int c    = lane & 15;

    const int srow  = tid >> 1;
    const int skoff = (tid & 1) * 16;
    const int brow_g = min(Nbase + srow, L_LABELS - 1);

    f32x4 acc[4][4] = {};

    for (int Kb = 0; Kb < D_DIM; Kb += FBK) {
        const float* gA = P   + (size_t)(Mbase + srow) * D_DIM + Kb + skoff;
        const float* gB = Lab + (size_t)brow_g        * D_DIM + Kb + skoff;
        #pragma unroll
        for (int i = 0; i < 4; ++i) {
            float4 va = *(const float4*)(gA + i * 4);
            float4 vb = *(const float4*)(gB + i * 4);
            *(bf16x4*)&As[srow][skoff + i * 4] =
                (bf16x4){(__bf16)va.x, (__bf16)va.y, (__bf16)va.z, (__bf16)va.w};
            *(bf16x4*)&Bs[srow][skoff + i * 4] =
                (bf16x4){(__bf16)vb.x, (__bf16)vb.y, (__bf16)vb.z, (__bf16)vb.w};
        }
        __syncthreads();

        bf16x8 afr[4], bfr[4];
        #pragma unroll
        for (int mi = 0; mi < 4; ++mi)
            afr[mi] = *(const bf16x8*)&As[wm * 64 + mi * 16 + c][quad * 8];
        #pragma unroll
        for (int ni = 0; ni < 4; ++ni)
            bfr[ni] = *(const bf16x8*)&Bs[wn * 64 + ni * 16 + c][quad * 8];

        #pragma unroll
        for (int mi = 0; mi < 4; ++mi)
            #pragma unroll
            for (int ni = 0; ni < 4; ++ni)
                acc[mi][ni] = __builtin_amdgcn_mfma_f32_16x16x32_bf16(
                    afr[mi], bfr[ni], acc[mi][ni], 0, 0, 0);
        __syncthreads();
    }

    #pragma unroll
    for (int mi = 0; mi < 4; ++mi) {
        int rowb = Mbase + wm * 64 + mi * 16 + quad * 4;
        #pragma unroll
        for (int r = 0; r < 4; ++r) {
            int   row = rowb + r;
            float st  = s_t[row];
            int   t   = labels[row];
            int   cnt = 0;
            #pragma unroll
            for (int ni = 0; ni < 4; ++ni) {
                int   n = Nbase + wn * 64 + ni * 16 + c;
                float s = acc[mi][ni][r];
                bool beat = (n < L_LABELS) && (n != t) &&
                            (s > st || (s == st && n < t));
                cnt += beat ? 1 : 0;
            }
            cnt += __shfl_xor(cnt, 1, 64);
            cnt += __shfl_xor(cnt, 2, 64);
            cnt += __shfl_xor(cnt, 4, 64);
            cnt += __shfl_xor(cnt, 8, 64);
            if (c == 0 && cnt) atomicAdd(&counts[row], cnt);
        }
    }
}

// ---------------------------------------------------------------------------
// Kernel 5: accuracy = mean(count1 + count2 < TOPK).
// ---------------------------------------------------------------------------
__global__ void finalize_kernel(const int* __restrict__ counts,
                                const int* __restrict__ counts2,
                                float* __restrict__ out) {
    __shared__ int sdata[4];
    int tid = threadIdx.x;
    int local = 0;
    for (int i = tid; i < B_ROWS; i += 256)
        local += (counts[i] + counts2[i] < TOPK) ? 1 : 0;
    #pragma unroll
    for (int m = 1; m < 64; m <<= 1) local += __shfl_xor(local, m, 64);
    if ((tid & 63) == 0) sdata[tid >> 6] = local;
    __syncthreads();
    if (tid == 0)
        out[0] = (float)(sdata[0] + sdata[1] + sdata[2] + sdata[3]) /
                 (float)B_ROWS;
}

extern "C" void kernel_launch(void* const* d_in, const int* in_sizes, int n_in,
                              void* d_out, int out_size, void* d_ws, size_t ws_size,
                              hipStream_t stream) {
    const float* P      = (const float*)d_in[0];
    const float* Lab    = (const float*)d_in[1];
    const int*   labels = (const int*)d_in[2];
    float* out = (float*)d_out;

    float* s_t     = (float*)d_ws;
    int*   counts  = (int*)((char*)d_ws + 16384);
    int*   counts2 = (int*)((char*)d_ws + 32768);
    int*   surv    = (int*)((char*)d_ws + 49152);
    int*   nsurv   = (int*)((char*)d_ws + 65536);

    const size_t pb_off = 69632;
    const size_t lb_off = pb_off + (size_t)B_ROWS * D_DIM * 2;   // +2 MB
    const size_t need   = lb_off + (size_t)CUT * D_DIM * 2;      // ~3.2 MB

    int fast = (ws_size >= need) ? 1 : 0;
    __hip_bfloat16* Pb = (__hip_bfloat16*)((char*)d_ws + pb_off);
    __hip_bfloat16* Lb = (__hip_bfloat16*)((char*)d_ws + lb_off);

    prep_kernel<<<dim3(B_ROWS / 4), 256, 0, stream>>>(
        P, Lab, labels, s_t, counts, counts2, Pb, Lb, nsurv, fast);

    if (fast) {
        count_kernel_c1<<<dim3(NGROUP, B_ROWS / CBM), 512, 0, stream>>>(
            Pb, Lb, labels, s_t, counts);
        compact_kernel<<<dim3(B_ROWS / 256), 256, 0, stream>>>(counts, surv, nsurv);
        count_kernel_p2<<<dim3(P2_BLOCKS), 256, 0, stream>>>(
            Pb, Lab, labels, s_t, surv, nsurv, counts2);
    } else {
        dim3 grid((L_LABELS + FBN - 1) / FBN, B_ROWS / FBM);
        count_kernel_slow<<<grid, 256, 0, stream>>>(P, Lab, labels, s_t, counts);
    }

    finalize_kernel<<<1, 256, 0, stream>>>(counts, counts2, out);
}